// Round 18
// baseline (105.972 us; speedup 1.0000x reference)
//
#include <hip/hip_runtime.h>
#include <math.h>

#define T_SEQ 2048
#define DIM   1024
#define HD3   3072
#define NH    16
#define HD    64
#define EPSF  1e-4f
#define MB    1048576

typedef __attribute__((ext_vector_type(8))) short bf16x8;
typedef __attribute__((ext_vector_type(4))) float f32x4;
typedef __attribute__((ext_vector_type(16))) float f32x16;
typedef __attribute__((ext_vector_type(4))) unsigned int u32x4;
typedef __attribute__((ext_vector_type(4))) unsigned short u16x4;

__device__ __forceinline__ ushort f2bf(float f) {
  unsigned int u = __float_as_uint(f);
  unsigned int r = (u + 0x7FFFu + ((u >> 16) & 1u)) >> 16;
  return (ushort)r;
}
__device__ __forceinline__ float bf2f(ushort u) {
  return __uint_as_float(((unsigned int)u) << 16);
}
// hardware packed f32x2 -> bf16x2 (lo = a, hi = b)
__device__ __forceinline__ unsigned int pk2(float a, float b) {
  unsigned int r;
  asm("v_cvt_pk_bf16_f32 %0, %1, %2" : "=v"(r) : "v"(a), "v"(b));
  return r;
}
__device__ __forceinline__ float waveSum(float v) {
#pragma unroll
  for (int o = 32; o > 0; o >>= 1) v += __shfl_xor(v, o, 64);
  return v;
}

#define GLOAD(gp, lp) __builtin_amdgcn_global_load_lds( \
    (const __attribute__((address_space(1))) unsigned int*)(gp), \
    (__attribute__((address_space(3))) unsigned int*)(lp), 16, 0, 0)

// ---------- 1) logmap (wave-per-token, no barriers) + weight cvt fused ----------
__global__ void logmap_cvt(const float* __restrict__ x,
                           ushort* __restrict__ xhyp,
                           float* __restrict__ ref_out,
                           const float* __restrict__ wa,
                           const float* __restrict__ wb,
                           ushort* __restrict__ da,
                           ushort* __restrict__ db) {
  if (blockIdx.x >= T_SEQ / 4) {
    int i = (blockIdx.x - T_SEQ / 4) * 256 + threadIdx.x;   // 0..524287
    const float* src; ushort* dst; int j;
    if (i < 393216) { src = wa; dst = da; j = i; }
    else            { src = wb; dst = db; j = i - 393216; }
    float4 a = ((const float4*)src)[j * 2];
    float4 b = ((const float4*)src)[j * 2 + 1];
    bf16x8 v;
    v[0] = f2bf(a.x); v[1] = f2bf(a.y); v[2] = f2bf(a.z); v[3] = f2bf(a.w);
    v[4] = f2bf(b.x); v[5] = f2bf(b.y); v[6] = f2bf(b.z); v[7] = f2bf(b.w);
    *(bf16x8*)(dst + (size_t)j * 8) = v;
    return;
  }
  int w = threadIdx.x >> 6, lane = threadIdx.x & 63;
  int t = blockIdx.x * 4 + w;
  const float4* xt = (const float4*)(x + (size_t)t * DIM);
  float4* refo = (float4*)(ref_out + (size_t)t * DIM);
  float4 xv[4], rv[4];
  float xn2 = 0.f, yn2 = 0.f, ip = 0.f;
#pragma unroll
  for (int i = 0; i < 4; i++) {
    int e = i * 64 + lane;
    float4 X = xt[e];
    float4 R = (t > 0) ? xt[e - 256] : float4{0.f, 0.f, 0.f, 0.f};
    xv[i] = X; rv[i] = R;
    yn2 += X.x * X.x + X.y * X.y + X.z * X.z + X.w * X.w;
    xn2 += R.x * R.x + R.y * R.y + R.z * R.z + R.w * R.w;
    ip  -= R.x * X.x + R.y * X.y + R.z * X.z + R.w * X.w;
    refo[e] = R;
  }
  xn2 = waveSum(xn2);
  yn2 = waveSum(yn2);
  ip  = waveSum(ip);
  float a = 1.f + 2.f * ip + yn2;
  float b = 1.f - xn2;
  float den = fmaxf(1.f + 2.f * ip + xn2 * yn2, EPSF);
  float invden = 1.f / den;
  float4 mob[4];
  float mn2 = 0.f;
#pragma unroll
  for (int i = 0; i < 4; i++) {
    float4 m;
    m.x = (-a * rv[i].x + b * xv[i].x) * invden;
    m.y = (-a * rv[i].y + b * xv[i].y) * invden;
    m.z = (-a * rv[i].z + b * xv[i].z) * invden;
    m.w = (-a * rv[i].w + b * xv[i].w) * invden;
    mob[i] = m;
    mn2 += m.x * m.x + m.y * m.y + m.z * m.z + m.w * m.w;
  }
  mn2 = waveSum(mn2);
  float mn  = sqrtf(mn2);
  float sf  = 2.f / (1.f + xn2);
  float cf  = 2.f / (sf + EPSF);
  float arg = fminf(sqrtf(mn), 0.99f);
  float mult = cf * atanhf(arg) / (mn + EPSF);
  u16x4* xo = (u16x4*)(xhyp + (size_t)t * DIM);
#pragma unroll
  for (int i = 0; i < 4; i++) {
    u16x4 u;
    u[0] = f2bf(mult * mob[i].x);
    u[1] = f2bf(mult * mob[i].y);
    u[2] = f2bf(mult * mob[i].z);
    u[3] = f2bf(mult * mob[i].w);
    xo[i * 64 + lane] = u;
  }
}

// ---------- 2) C = A * W^T, 2-phase dbuf pipeline, XCD-swizzled block map ----------
// EPI=0: plain f32 C store (gemm2, BM=64).
// EPI=1 (BM=128, gemm1 qkv): fused rms+rotary+fragment-pack epilogue.
// Epilogue tile OVERLAYS As/Bs (dead after K loop) -> 32KB LDS, 3 blocks/CU.
template<int BM, int EPI>
__global__ __launch_bounds__(256, 3) void gemm_bf16(const ushort* __restrict__ A,
                                                    const ushort* __restrict__ W,
                                                    float* __restrict__ C,
                                                    ushort* __restrict__ qfr,
                                                    ushort* __restrict__ kfr,
                                                    ushort* __restrict__ vfr,
                                                    int M, int N, int K) {
  __shared__ ushort As[2][BM * 32];
  __shared__ ushort Bs[2][128 * 32];
  constexpr int NF = (BM == 128) ? 4 : 2;
  // bijective XCD swizzle (grid % 8 == 0): contiguous output chunk per XCD
  int nwg = gridDim.x * gridDim.y;
  int wgid = blockIdx.y * gridDim.x + blockIdx.x;
  int swz = (wgid & 7) * (nwg >> 3) + (wgid >> 3);
  int bxx = swz % gridDim.x, byy = swz / gridDim.x;
  int tid = threadIdx.x;
  int lane = tid & 63, w = tid >> 6;
  int row_base = (BM == 128) ? (w >> 1) * 64 : 0;
  int col_base = (BM == 128) ? (w & 1) * 64 : w * 32;
  int g = lane >> 4, cc = lane & 15;
  int bm = byy * BM, bn = bxx * 128;
  f32x4 acc[4][NF] = {};

  {
    if constexpr (BM == 128) {
#pragma unroll
      for (int i = 0; i < 2; i++) {
        int ch = i * 256 + tid;
        GLOAD(A + (size_t)(bm + (ch >> 2)) * K + (ch & 3) * 8, &As[0][ch * 8]);
      }
    } else {
      int ch = tid;
      GLOAD(A + (size_t)(bm + (ch >> 2)) * K + (ch & 3) * 8, &As[0][ch * 8]);
    }
#pragma unroll
    for (int i = 0; i < 2; i++) {
      int ch = i * 256 + tid;
      GLOAD(W + (size_t)(bn + (ch >> 2)) * K + (ch & 3) * 8, &Bs[0][ch * 8]);
    }
  }
  __syncthreads();

  int cur = 0;
  for (int kt = 0; kt < K; kt += 32) {
    if (kt + 32 < K) {
      int nxt = cur ^ 1;
      if constexpr (BM == 128) {
#pragma unroll
        for (int i = 0; i < 2; i++) {
          int ch = i * 256 + tid;
          GLOAD(A + (size_t)(bm + (ch >> 2)) * K + kt + 32 + (ch & 3) * 8, &As[nxt][ch * 8]);
        }
      } else {
        int ch = tid;
        GLOAD(A + (size_t)(bm + (ch >> 2)) * K + kt + 32 + (ch & 3) * 8, &As[nxt][ch * 8]);
      }
#pragma unroll
      for (int i = 0; i < 2; i++) {
        int ch = i * 256 + tid;
        GLOAD(W + (size_t)(bn + (ch >> 2)) * K + kt + 32 + (ch & 3) * 8, &Bs[nxt][ch * 8]);
      }
    }
    bf16x8 af[4], bfr[NF];
#pragma unroll
    for (int m = 0; m < 4; m++)
      af[m] = *(const bf16x8*)&As[cur][(row_base + m * 16 + cc) * 32 + 8 * g];
#pragma unroll
    for (int n = 0; n < NF; n++)
      bfr[n] = *(const bf16x8*)&Bs[cur][(col_base + n * 16 + cc) * 32 + 8 * g];
#pragma unroll
    for (int m = 0; m < 4; m++)
#pragma unroll
      for (int n = 0; n < NF; n++)
        acc[m][n] = __builtin_amdgcn_mfma_f32_16x16x32_bf16(af[m], bfr[n], acc[m][n], 0, 0, 0);
    __syncthreads();
    cur ^= 1;
  }

  if constexpr (EPI == 0) {
#pragma unroll
    for (int m = 0; m < 4; m++)
#pragma unroll
      for (int n = 0; n < NF; n++)
#pragma unroll
        for (int j = 0; j < 4; j++)
          C[(size_t)(bm + row_base + m * 16 + g * 4 + j) * N + bn + col_base + n * 16 + cc] = acc[m][n][j];
  } else {
    // wave-private 64x64 tile overlaid on dead staging LDS (post-barrier safe)
    ushort* tbase = (w < 2) ? &As[w][0] : &Bs[w - 2][0];
    ushort (*tile)[64] = (ushort(*)[64])tbase;
    int region = bxx >> 3;                 // 0=Q 1=K 2=V
    int hh = ((bxx & 7) << 1) | (w & 1);   // head
    int tokbase = byy * 128 + (w >> 1) * 64;
    if (region < 2) {
      float rinv[4][4];
#pragma unroll
      for (int m = 0; m < 4; m++)
#pragma unroll
        for (int j = 0; j < 4; j++) {
          float ss = acc[m][0][j] * acc[m][0][j] + acc[m][1][j] * acc[m][1][j]
                   + acc[m][2][j] * acc[m][2][j] + acc[m][3][j] * acc[m][3][j];
          ss += __shfl_xor(ss, 1, 64);
          ss += __shfl_xor(ss, 2, 64);
          ss += __shfl_xor(ss, 4, 64);
          ss += __shfl_xor(ss, 8, 64);
          rinv[m][j] = rsqrtf(ss * (1.f / 64.f) + 1.1920929e-07f);
        }
      float freq = exp2f(-(10.f / 15.f) * (float)cc);
#pragma unroll
      for (int m = 0; m < 4; m++)
#pragma unroll
        for (int j = 0; j < 4; j++) {
          int row = m * 16 + g * 4 + j;
          float sth, cth;
          sincosf((float)(tokbase + row) * freq, &sth, &cth);
          float ri = rinv[m][j];
          float x0 = acc[m][0][j] * ri;
          float x2 = acc[m][2][j] * ri;
          int sz = (row & 7) << 3;
          tile[row][(0 * 16 + cc) ^ sz] = f2bf(x0 * cth + x2 * sth);
          tile[row][(1 * 16 + cc) ^ sz] = f2bf(acc[m][1][j] * ri);
          tile[row][(2 * 16 + cc) ^ sz] = f2bf(-x0 * sth + x2 * cth);
          tile[row][(3 * 16 + cc) ^ sz] = f2bf(acc[m][3][j] * ri);
        }
    } else {
#pragma unroll
      for (int m = 0; m < 4; m++)
#pragma unroll
        for (int n = 0; n < 4; n++)
#pragma unroll
          for (int j = 0; j < 4; j++) {
            int trow = m * 16 + g * 4 + j;   // token
            int d = n * 16 + cc;             // dim
            tile[d][trow ^ ((d & 7) << 3)] = f2bf(acc[m][n][j]);
          }
    }
    int q31 = lane & 31, hi = lane >> 5;
#pragma unroll
    for (int grp = 0; grp < 2; grp++)
#pragma unroll
      for (int st = 0; st < 4; st++) {
        int r = grp * 32 + q31;
        bf16x8 v8 = *(const bf16x8*)&tile[r][(st * 16 + 8 * hi) ^ ((r & 7) << 3)];
        if (region == 0) {
          int qt = byy * 4 + (w >> 1) * 2 + grp;
          *(bf16x8*)&qfr[(((size_t)hh * 64 + qt) * 4 + st) * 512 + lane * 8] = v8;
        } else {
          int kblk = byy * 2 + (w >> 1);
          size_t dst = ((((size_t)hh * 32 + kblk) * 2 + grp) * 4 + st) * 512 + lane * 8;
          if (region == 1) *(bf16x8*)&kfr[dst] = v8;
          else             *(bf16x8*)&vfr[dst] = v8;
        }
      }
  }
}

// ---------- 4) causal flash attention, K-refill pipeline, 512-key chunks ----------
// task = (head, 32-query tile qt, 512-key chunk ch), nch(qt)=qt/16+1,
// 160 tasks/head -> 2560 waves. Compact prefix records (11.1 MB).
__global__ __launch_bounds__(256, 2) void attn_mfma(const ushort* __restrict__ qfr,
                                                    const ushort* __restrict__ kfr,
                                                    const ushort* __restrict__ vfr,
                                                    ushort* __restrict__ parts) {
  int lane = threadIdx.x & 63;
  int hi = lane >> 5;
  int q31 = lane & 31;
  int w = threadIdx.x >> 6;
  int tid = blockIdx.x * 4 + w;
  int h = tid / 160;
  int s = 159 - (tid % 160);   // heavy tasks first
  // decode s -> (qt, ch): group g = qt>>4, base_g = 8g(g+1)
  int g = 0;
  while (8 * (g + 1) * (g + 2) <= s) ++g;
  int rem = s - 8 * g * (g + 1);
  int qi = rem / (g + 1);
  int ch = rem - qi * (g + 1);
  int qt = 16 * g + qi;
  int qbase  = qt * 32;
  int kstart = ch * 512;
  int kend   = min(kstart + 512, qbase + 32);
  bool fin   = (kend == qbase + 32);
  int nt     = (kend - kstart + 63) >> 6;   // 1..8 64-key tiles

  bf16x8 qf[4];
  {
    const ushort* qb8 = qfr + (((size_t)h * 64 + qt) * 4) * 512 + lane * 8;
#pragma unroll
    for (int st = 0; st < 4; st++)
      qf[st] = *(const bf16x8*)(qb8 + st * 512);
  }
  // prologue: K fragments for tile 0
  bf16x8 kc[8];
  {
    const ushort* kb8 = kfr + ((((size_t)h * 32 + (kstart >> 6)) * 2) * 4) * 512 + lane * 8;
#pragma unroll
    for (int st = 0; st < 8; st++)
      kc[st] = *(const bf16x8*)(kb8 + st * 512);
  }

  f32x16 acc0 = {}, acc1 = {};
  float lrow = 0.f;
  int qglob = qbase + q31;
  const float SC = 0.12f * 1.44269504f;

  for (int ti = 0; ti < nt; ti++) {
    int k0 = kstart + ti * 64;
    int kblk = k0 >> 6;
    const ushort* vb8 = vfr + ((((size_t)h * 32 + kblk) * 2) * 4) * 512 + lane * 8;
    f32x16 cA = {}, cB = {};
    __builtin_amdgcn_s_setprio(1);
#pragma unroll
    for (int st = 0; st < 4; st++) {
      cA = __builtin_amdgcn_mfma_f32_32x32x16_bf16(kc[st], qf[st], cA, 0, 0, 0);
      cB = __builtin_amdgcn_mfma_f32_32x32x16_bf16(kc[4 + st], qf[st], cB, 0, 0, 0);
    }
    __builtin_amdgcn_s_setprio(0);
    // refill K for next tile + load V now; latency hides under softmax/pack
    if (ti + 1 < nt) {
      const ushort* nk = kfr + ((((size_t)h * 32 + kblk + 1) * 2) * 4) * 512 + lane * 8;
#pragma unroll
      for (int st = 0; st < 8; st++)
        kc[st] = *(const bf16x8*)(nk + st * 512);
    }
    bf16x8 vv[8];
#pragma unroll
    for (int st = 0; st < 8; st++)
      vv[st] = *(const bf16x8*)(vb8 + st * 512);
    __builtin_amdgcn_sched_barrier(0);   // pin load issue above the VALU section
    float p[32];
#pragma unroll
    for (int r = 0; r < 16; r++) {
      float sA = cA[r] * SC;
      float sB = cB[r] * SC;
      if (fin) {
        int key = k0 + (r & 3) + 8 * (r >> 2) + 4 * hi;
        if (key > qglob)      sA = -1e30f;
        if (key + 32 > qglob) sB = -1e30f;
      }
      p[r] = sA;
      p[16 + r] = sB;
    }
    float rs0 = 0.f, rs1 = 0.f;
#pragma unroll
    for (int r = 0; r < 16; r++) {
      p[r]      = exp2f(p[r]);      rs0 += p[r];
      p[16 + r] = exp2f(p[16 + r]); rs1 += p[16 + r];
    }
    float rs = rs0 + rs1;
    rs += __shfl_xor(rs, 32, 64);
    lrow += rs;
    unsigned int pw[16], sw[16];
#pragma unroll
    for (int j = 0; j < 16; j++)
      pw[j] = pk2(p[2 * j], p[2 * j + 1]);
#pragma unroll
    for (int j = 0; j < 16; j++)
      sw[j] = __shfl_xor(pw[j], 32, 64);
    u32x4 u0, u1, u2, u3;
    u0[0] = hi ? sw[2]  : pw[0];
    u0[1] = hi ? sw[3]  : pw[1];
    u0[2] = hi ? pw[2]  : sw[0];
    u0[3] = hi ? pw[3]  : sw[1];
    u1[0] = hi ? sw[6]  : pw[4];
    u1[1] = hi ? sw[7]  : pw[5];
    u1[2] = hi ? pw[6]  : sw[4];
    u1[3] = hi ? pw[7]  : sw[5];
    u2[0] = hi ? sw[10] : pw[8];
    u2[1] = hi ? sw[11] : pw[9];
    u2[2] = hi ? pw[10] : sw[8];
    u2[3] = hi ? pw[11] : sw[9];
    u3[0] = hi ? sw[14] : pw[12];
    u3[1] = hi ? sw[15] : pw[13];
    u3[2] = hi ? pw[14] : sw[12];
    u3[3] = hi ? pw[15] : sw[13];
    bf16x8 pbA0 = __builtin_bit_cast(bf16x8, u0);
    bf16x8 pbA1 = __builtin_bit_cast(bf16x8, u1);
    bf16x8 pbB0 = __builtin_bit_cast(bf16x8, u2);
    bf16x8 pbB1 = __builtin_bit_cast(bf16x8, u3);
    __builtin_amdgcn_s_setprio(1);
    acc0 = __builtin_amdgcn_mfma_f32_32x32x16_bf16(vv[0], pbA0, acc0, 0, 0, 0);
    acc1 = __builtin_amdgcn_mfma_f32_32x32x16_bf16(vv[4], pbA0, acc1, 0, 0, 0);
    acc0 = __builtin_amdgcn_mfma_f32_32x32x16_bf16(vv[1], pbA1, acc0, 0, 0, 0);
    acc1 = __builtin_amdgcn_mfma_f32_32x32x16_bf16(vv[5], pbA1, acc1, 0, 0, 0);
    acc0 = __builtin_amdgcn_mfma_f32_32x32x16_bf16(vv[2], pbB0, acc0, 0, 0, 0);
    acc1 = __builtin_amdgcn_mfma_f32_32x32x16_bf16(vv[6], pbB0, acc1, 0, 0, 0);
    acc0 = __builtin_amdgcn_mfma_f32_32x32x16_bf16(vv[3], pbB1, acc0, 0, 0, 0);
    acc1 = __builtin_amdgcn_mfma_f32_32x32x16_bf16(vv[7], pbB1, acc1, 0, 0, 0);
    __builtin_amdgcn_s_setprio(0);
  }
  ushort* rec = parts + (size_t)(h * 160 + s) * 2176;
#pragma unroll
  for (int r = 0; r < 16; r++) {
    int d = (r & 3) + 8 * (r >> 2) + 4 * hi;
    rec[q31 * 64 + d]      = f2bf(acc0[r]);
    rec[q31 * 64 + 32 + d] = f2bf(acc1[r]);
  }
  if (!hi)
    *(float*)((char*)rec + 4096 + q31 * 4) = lrow;
}

// ---------- 4b) merge split-K partials: pure sum; 2 rows/wave, u32 loads ----------
__global__ __launch_bounds__(256) void attn_merge(const ushort* __restrict__ parts,
                                                  ushort* __restrict__ o) {
  int w = threadIdx.x >> 6, lane = threadIdx.x & 63;
  int idx = blockIdx.x * 8 + w * 2 + (lane >> 5);   // (h*64 + qt)*32 + r
  int l32 = lane & 31;
  int r = idx & 31;
  int rec_i = idx >> 5;
  int qt = rec_i & 63, h = rec_i >> 6;
  int g = qt >> 4, rr = qt & 15;
  int nch = g + 1;
  int off = 8 * g * (g + 1) + rr * (g + 1);   // prefix record offset
  const ushort* base = parts + (size_t)(h * 160 + off) * 2176;
  float L = 0.f, ox = 0.f, oy = 0.f;
#pragma unroll
  for (int i = 0; i < 4; i++) {
    if (i < nch) {
      L += *(const float*)((const char*)base + i * 4352 + 4096 + r * 4);
      unsigned int u = *(const unsigned int*)(base + i * 2176 + r * 64 + l32 * 2);
      ox += bf2f((ushort)(u & 0xffffu));
      oy += bf2f((ushort)(u >> 16));
    }
  }
  float invL = 1.f / L;
  unsigned int o2 = pk2(ox * invL, oy * invL);
  *(unsigned int*)(o + (size_t)(qt * 32 + r) * DIM + h * HD + l32 * 2) = o2;
}

// ---------- 6) expmap (wave-per-token, no barriers) ----------
__global__ void expmap_kernel(const float* __restrict__ y2,
                              const float* __restrict__ ref,
                              float* __restrict__ yout) {
  int w = threadIdx.x >> 6, lane = threadIdx.x & 63;
  int t = blockIdx.x * 4 + w;
  const float4* Rp = (const float4*)(ref + (size_t)t * DIM);
  const float4* Vp = (const float4*)(y2 + (size_t)t * DIM);
  float4 X[4], V[4];
  float xn2 = 0.f, vn2 = 0.f, xv = 0.f;
#pragma unroll
  for (int i = 0; i < 4; i++) {
    int e = i * 64 + lane;
    float4 Xi = Rp[e], Vi = Vp[e];
    X[i] = Xi; V[i] = Vi;
    xn2 += Xi.x * Xi.x + Xi.y * Xi.y + Xi.z * Xi.z + Xi.w * Xi.w;
    vn2 += Vi.x * Vi.x + Vi.y * Vi.y + Vi.z * Vi.z + Vi.w * Vi.w;
    xv  += Xi.x * Vi.x + Xi.y * Vi.y + Xi.z * Vi.z + Xi.w * Vi.w;
  }
  xn2 = waveSum(xn2);
  vn2 = waveSum(vn2);
  xv  = waveSum(xv);
  float vn  = sqrtf(vn2);
  float sf  = 2.f / (1.f + xn2);
  float arg = sqrtf(fminf(fmaxf(0.5f * sf * vn2, 0.f), 8.f));
  float scl = tanhf(arg) / (vn + EPSF);
  float yn2 = scl * scl * vn2;
  float ip  = scl * xv;
  float A = 1.f + 2.f * ip + yn2;
  float B = (1.f - xn2) * scl;
  float den = fmaxf(1.f + 2.f * ip + xn2 * yn2, EPSF);
  float invden = 1.f / den;
  float4* outp = (float4*)(yout + (size_t)t * DIM);
#pragma unroll
  for (int i = 0; i < 4; i++) {
    float4 o;
    o.x = (A * X[i].x + B * V[i].x) * invden;
    o.y = (A * X[i].y + B * V[i].y) * invden;
    o.z = (A * X[i].z + B * V[i].z) * invden;
    o.w = (A * X[i].w + B * V[i].w) * invden;
    outp[i * 64 + lane] = o;
  }
}

// ---------- launch ----------
extern "C" void kernel_launch(void* const* d_in, const int* in_sizes, int n_in,
                              void* d_out, int out_size, void* d_ws, size_t ws_size,
                              hipStream_t stream) {
  const float* x        = (const float*)d_in[0];
  const float* qkv_w    = (const float*)d_in[1];
  const float* c_proj_w = (const float*)d_in[2];
  float* out = (float*)d_out;
  char*  W   = (char*)d_ws;

  ushort* qkvw_bf   = (ushort*)(W);             // [0, 6MB)
  ushort* cprojw_bf = (ushort*)(W + 6  * MB);   // [6, 8MB)
  ushort* xhyp_bf   = (ushort*)(W + 8  * MB);   // [8, 12MB)  reused as attn out o
  float*  y2        = (float*) (W + 12 * MB);   // [12, 36MB) shared: parts then y2
  ushort* parts     = (ushort*)(W + 12 * MB);   // 11.1 MB (dead before y2 written)
  ushort* qfrag     = (ushort*)(W + 36 * MB);   // [36, 40MB)
  ushort* kfrag     = (ushort*)(W + 40 * MB);   // [40, 44MB)
  ushort* vfrag     = (ushort*)(W + 44 * MB);   // [44, 48MB)
  ushort* obuf      = xhyp_bf;
  float*  ref       = out + (size_t)T_SEQ * DIM;

  logmap_cvt<<<T_SEQ / 4 + 2048, 256, 0, stream>>>(x, xhyp_bf, ref, qkv_w, c_proj_w,
                                                   qkvw_bf, cprojw_bf);
  gemm_bf16<128, 1><<<dim3(HD3 / 128, T_SEQ / 128), 256, 0, stream>>>(
      xhyp_bf, qkvw_bf, nullptr, qfrag, kfrag, vfrag, T_SEQ, HD3, DIM);
  attn_mfma<<<640, 256, 0, stream>>>(qfrag, kfrag, vfrag, parts);
  attn_merge<<<4096, 256, 0, stream>>>(parts, obuf);
  gemm_bf16<64, 0><<<dim3(DIM / 128, T_SEQ / 64), 256, 0, stream>>>(
      obuf, cprojw_bf, y2, nullptr, nullptr, nullptr, T_SEQ, DIM, DIM);
  expmap_kernel<<<T_SEQ / 4, 256, 0, stream>>>(y2, ref, out);
}

// Round 19
// 102.882 us; speedup vs baseline: 1.0300x; 1.0300x over previous
//
#include <hip/hip_runtime.h>
#include <math.h>

#define T_SEQ 2048
#define DIM   1024
#define HD3   3072
#define NH    16
#define HD    64
#define EPSF  1e-4f
#define MB    1048576

typedef __attribute__((ext_vector_type(8))) short bf16x8;
typedef __attribute__((ext_vector_type(4))) float f32x4;
typedef __attribute__((ext_vector_type(16))) float f32x16;
typedef __attribute__((ext_vector_type(4))) unsigned int u32x4;
typedef __attribute__((ext_vector_type(4))) unsigned short u16x4;

__device__ __forceinline__ ushort f2bf(float f) {
  unsigned int u = __float_as_uint(f);
  unsigned int r = (u + 0x7FFFu + ((u >> 16) & 1u)) >> 16;
  return (ushort)r;
}
__device__ __forceinline__ float bf2f(ushort u) {
  return __uint_as_float(((unsigned int)u) << 16);
}
// hardware packed f32x2 -> bf16x2 (lo = a, hi = b)
__device__ __forceinline__ unsigned int pk2(float a, float b) {
  unsigned int r;
  asm("v_cvt_pk_bf16_f32 %0, %1, %2" : "=v"(r) : "v"(a), "v"(b));
  return r;
}
__device__ __forceinline__ float waveSum(float v) {
#pragma unroll
  for (int o = 32; o > 0; o >>= 1) v += __shfl_xor(v, o, 64);
  return v;
}

#define GLOAD(gp, lp) __builtin_amdgcn_global_load_lds( \
    (const __attribute__((address_space(1))) unsigned int*)(gp), \
    (__attribute__((address_space(3))) unsigned int*)(lp), 16, 0, 0)

// ---------- 1) logmap (wave-per-token, no barriers) + weight cvt fused ----------
__global__ void logmap_cvt(const float* __restrict__ x,
                           ushort* __restrict__ xhyp,
                           float* __restrict__ ref_out,
                           const float* __restrict__ wa,
                           const float* __restrict__ wb,
                           ushort* __restrict__ da,
                           ushort* __restrict__ db) {
  if (blockIdx.x >= T_SEQ / 4) {
    int i = (blockIdx.x - T_SEQ / 4) * 256 + threadIdx.x;   // 0..524287
    const float* src; ushort* dst; int j;
    if (i < 393216) { src = wa; dst = da; j = i; }
    else            { src = wb; dst = db; j = i - 393216; }
    float4 a = ((const float4*)src)[j * 2];
    float4 b = ((const float4*)src)[j * 2 + 1];
    bf16x8 v;
    v[0] = f2bf(a.x); v[1] = f2bf(a.y); v[2] = f2bf(a.z); v[3] = f2bf(a.w);
    v[4] = f2bf(b.x); v[5] = f2bf(b.y); v[6] = f2bf(b.z); v[7] = f2bf(b.w);
    *(bf16x8*)(dst + (size_t)j * 8) = v;
    return;
  }
  int w = threadIdx.x >> 6, lane = threadIdx.x & 63;
  int t = blockIdx.x * 4 + w;
  const float4* xt = (const float4*)(x + (size_t)t * DIM);
  float4* refo = (float4*)(ref_out + (size_t)t * DIM);
  float4 xv[4], rv[4];
  float xn2 = 0.f, yn2 = 0.f, ip = 0.f;
#pragma unroll
  for (int i = 0; i < 4; i++) {
    int e = i * 64 + lane;
    float4 X = xt[e];
    float4 R = (t > 0) ? xt[e - 256] : float4{0.f, 0.f, 0.f, 0.f};
    xv[i] = X; rv[i] = R;
    yn2 += X.x * X.x + X.y * X.y + X.z * X.z + X.w * X.w;
    xn2 += R.x * R.x + R.y * R.y + R.z * R.z + R.w * R.w;
    ip  -= R.x * X.x + R.y * X.y + R.z * X.z + R.w * X.w;
    refo[e] = R;
  }
  xn2 = waveSum(xn2);
  yn2 = waveSum(yn2);
  ip  = waveSum(ip);
  float a = 1.f + 2.f * ip + yn2;
  float b = 1.f - xn2;
  float den = fmaxf(1.f + 2.f * ip + xn2 * yn2, EPSF);
  float invden = 1.f / den;
  float4 mob[4];
  float mn2 = 0.f;
#pragma unroll
  for (int i = 0; i < 4; i++) {
    float4 m;
    m.x = (-a * rv[i].x + b * xv[i].x) * invden;
    m.y = (-a * rv[i].y + b * xv[i].y) * invden;
    m.z = (-a * rv[i].z + b * xv[i].z) * invden;
    m.w = (-a * rv[i].w + b * xv[i].w) * invden;
    mob[i] = m;
    mn2 += m.x * m.x + m.y * m.y + m.z * m.z + m.w * m.w;
  }
  mn2 = waveSum(mn2);
  float mn  = sqrtf(mn2);
  float sf  = 2.f / (1.f + xn2);
  float cf  = 2.f / (sf + EPSF);
  float arg = fminf(sqrtf(mn), 0.99f);
  float mult = cf * atanhf(arg) / (mn + EPSF);
  u16x4* xo = (u16x4*)(xhyp + (size_t)t * DIM);
#pragma unroll
  for (int i = 0; i < 4; i++) {
    u16x4 u;
    u[0] = f2bf(mult * mob[i].x);
    u[1] = f2bf(mult * mob[i].y);
    u[2] = f2bf(mult * mob[i].z);
    u[3] = f2bf(mult * mob[i].w);
    xo[i * 64 + lane] = u;
  }
}

// ---------- 2) C = A * W^T, 2-phase dbuf pipeline, XCD-swizzled block map ----------
// EPI=0: plain f32 C store (gemm2, BM=64), launch bounds as in r17.
// EPI=1 (BM=128, gemm1 qkv): fused rms+rotary+fragment-pack epilogue; the
// epilogue tile OVERLAYS the dead staging LDS -> 32KB total, 3 blocks/CU.
template<int BM, int EPI>
__global__ __launch_bounds__(256, EPI ? 3 : 1) void gemm_bf16(
    const ushort* __restrict__ A,
    const ushort* __restrict__ W,
    float* __restrict__ C,
    ushort* __restrict__ qfr,
    ushort* __restrict__ kfr,
    ushort* __restrict__ vfr,
    int M, int N, int K) {
  __shared__ ushort As[2][BM * 32];
  __shared__ ushort Bs[2][128 * 32];
  constexpr int NF = (BM == 128) ? 4 : 2;
  // bijective XCD swizzle (grid % 8 == 0): contiguous output chunk per XCD
  int nwg = gridDim.x * gridDim.y;
  int wgid = blockIdx.y * gridDim.x + blockIdx.x;
  int swz = (wgid & 7) * (nwg >> 3) + (wgid >> 3);
  int bxx = swz % gridDim.x, byy = swz / gridDim.x;
  int tid = threadIdx.x;
  int lane = tid & 63, w = tid >> 6;
  int row_base = (BM == 128) ? (w >> 1) * 64 : 0;
  int col_base = (BM == 128) ? (w & 1) * 64 : w * 32;
  int g = lane >> 4, cc = lane & 15;
  int bm = byy * BM, bn = bxx * 128;
  f32x4 acc[4][NF] = {};

  {
    if constexpr (BM == 128) {
#pragma unroll
      for (int i = 0; i < 2; i++) {
        int ch = i * 256 + tid;
        GLOAD(A + (size_t)(bm + (ch >> 2)) * K + (ch & 3) * 8, &As[0][ch * 8]);
      }
    } else {
      int ch = tid;
      GLOAD(A + (size_t)(bm + (ch >> 2)) * K + (ch & 3) * 8, &As[0][ch * 8]);
    }
#pragma unroll
    for (int i = 0; i < 2; i++) {
      int ch = i * 256 + tid;
      GLOAD(W + (size_t)(bn + (ch >> 2)) * K + (ch & 3) * 8, &Bs[0][ch * 8]);
    }
  }
  __syncthreads();

  int cur = 0;
  for (int kt = 0; kt < K; kt += 32) {
    if (kt + 32 < K) {
      int nxt = cur ^ 1;
      if constexpr (BM == 128) {
#pragma unroll
        for (int i = 0; i < 2; i++) {
          int ch = i * 256 + tid;
          GLOAD(A + (size_t)(bm + (ch >> 2)) * K + kt + 32 + (ch & 3) * 8, &As[nxt][ch * 8]);
        }
      } else {
        int ch = tid;
        GLOAD(A + (size_t)(bm + (ch >> 2)) * K + kt + 32 + (ch & 3) * 8, &As[nxt][ch * 8]);
      }
#pragma unroll
      for (int i = 0; i < 2; i++) {
        int ch = i * 256 + tid;
        GLOAD(W + (size_t)(bn + (ch >> 2)) * K + kt + 32 + (ch & 3) * 8, &Bs[nxt][ch * 8]);
      }
    }
    bf16x8 af[4], bfr[NF];
#pragma unroll
    for (int m = 0; m < 4; m++)
      af[m] = *(const bf16x8*)&As[cur][(row_base + m * 16 + cc) * 32 + 8 * g];
#pragma unroll
    for (int n = 0; n < NF; n++)
      bfr[n] = *(const bf16x8*)&Bs[cur][(col_base + n * 16 + cc) * 32 + 8 * g];
#pragma unroll
    for (int m = 0; m < 4; m++)
#pragma unroll
      for (int n = 0; n < NF; n++)
        acc[m][n] = __builtin_amdgcn_mfma_f32_16x16x32_bf16(af[m], bfr[n], acc[m][n], 0, 0, 0);
    __syncthreads();
    cur ^= 1;
  }

  if constexpr (EPI == 0) {
#pragma unroll
    for (int m = 0; m < 4; m++)
#pragma unroll
      for (int n = 0; n < NF; n++)
#pragma unroll
        for (int j = 0; j < 4; j++)
          C[(size_t)(bm + row_base + m * 16 + g * 4 + j) * N + bn + col_base + n * 16 + cc] = acc[m][n][j];
  } else {
    // wave-private 64x64 tile overlaid on dead staging LDS (post-barrier safe)
    ushort* tbase = (w < 2) ? &As[w][0] : &Bs[w - 2][0];
    ushort (*tile)[64] = (ushort(*)[64])tbase;
    int region = bxx >> 3;                 // 0=Q 1=K 2=V
    int hh = ((bxx & 7) << 1) | (w & 1);   // head
    int tokbase = byy * 128 + (w >> 1) * 64;
    if (region < 2) {
      float rinv[4][4];
#pragma unroll
      for (int m = 0; m < 4; m++)
#pragma unroll
        for (int j = 0; j < 4; j++) {
          float ss = acc[m][0][j] * acc[m][0][j] + acc[m][1][j] * acc[m][1][j]
                   + acc[m][2][j] * acc[m][2][j] + acc[m][3][j] * acc[m][3][j];
          ss += __shfl_xor(ss, 1, 64);
          ss += __shfl_xor(ss, 2, 64);
          ss += __shfl_xor(ss, 4, 64);
          ss += __shfl_xor(ss, 8, 64);
          rinv[m][j] = rsqrtf(ss * (1.f / 64.f) + 1.1920929e-07f);
        }
      float freq = exp2f(-(10.f / 15.f) * (float)cc);
#pragma unroll
      for (int m = 0; m < 4; m++)
#pragma unroll
        for (int j = 0; j < 4; j++) {
          int row = m * 16 + g * 4 + j;
          float sth, cth;
          sincosf((float)(tokbase + row) * freq, &sth, &cth);
          float ri = rinv[m][j];
          float x0 = acc[m][0][j] * ri;
          float x2 = acc[m][2][j] * ri;
          int sz = (row & 7) << 3;
          tile[row][(0 * 16 + cc) ^ sz] = f2bf(x0 * cth + x2 * sth);
          tile[row][(1 * 16 + cc) ^ sz] = f2bf(acc[m][1][j] * ri);
          tile[row][(2 * 16 + cc) ^ sz] = f2bf(-x0 * sth + x2 * cth);
          tile[row][(3 * 16 + cc) ^ sz] = f2bf(acc[m][3][j] * ri);
        }
    } else {
#pragma unroll
      for (int m = 0; m < 4; m++)
#pragma unroll
        for (int n = 0; n < 4; n++)
#pragma unroll
          for (int j = 0; j < 4; j++) {
            int trow = m * 16 + g * 4 + j;   // token
            int d = n * 16 + cc;             // dim
            tile[d][trow ^ ((d & 7) << 3)] = f2bf(acc[m][n][j]);
          }
    }
    int q31 = lane & 31, hi = lane >> 5;
#pragma unroll
    for (int grp = 0; grp < 2; grp++)
#pragma unroll
      for (int st = 0; st < 4; st++) {
        int r = grp * 32 + q31;
        bf16x8 v8 = *(const bf16x8*)&tile[r][(st * 16 + 8 * hi) ^ ((r & 7) << 3)];
        if (region == 0) {
          int qt = byy * 4 + (w >> 1) * 2 + grp;
          *(bf16x8*)&qfr[(((size_t)hh * 64 + qt) * 4 + st) * 512 + lane * 8] = v8;
        } else {
          int kblk = byy * 2 + (w >> 1);
          size_t dst = ((((size_t)hh * 32 + kblk) * 2 + grp) * 4 + st) * 512 + lane * 8;
          if (region == 1) *(bf16x8*)&kfr[dst] = v8;
          else             *(bf16x8*)&vfr[dst] = v8;
        }
      }
  }
}

// ---------- 4) causal flash attention, K-refill pipeline, 256-key chunks (r17) ----------
__global__ __launch_bounds__(256, 2) void attn_mfma(const ushort* __restrict__ qfr,
                                                    const ushort* __restrict__ kfr,
                                                    const ushort* __restrict__ vfr,
                                                    ushort* __restrict__ parts) {
  int lane = threadIdx.x & 63;
  int hi = lane >> 5;
  int q31 = lane & 31;
  int w = threadIdx.x >> 6;
  int tid = blockIdx.x * 4 + w;
  int h = tid / 288;
  int s = tid % 288;
  int g = (int)((sqrtf((float)s + 1.0f) - 1.0f) * 0.5f);
  while (4 * (g + 1) * (g + 2) <= s) ++g;
  while (4 * g * (g + 1) > s) --g;
  int rem = s - 4 * g * (g + 1);
  int qi8 = rem / (g + 1);
  int ch  = rem - qi8 * (g + 1);
  int qt  = 8 * g + qi8;
  int qbase  = qt * 32;
  int kstart = ch * 256;
  int kend   = min(kstart + 256, qbase + 32);
  bool fin   = (kend == qbase + 32);
  int nt     = (kend - kstart + 63) >> 6;

  bf16x8 qf[4];
  {
    const ushort* qb8 = qfr + (((size_t)h * 64 + qt) * 4) * 512 + lane * 8;
#pragma unroll
    for (int st = 0; st < 4; st++)
      qf[st] = *(const bf16x8*)(qb8 + st * 512);
  }
  // prologue: K fragments for tile 0
  bf16x8 kc[8];
  {
    const ushort* kb8 = kfr + ((((size_t)h * 32 + (kstart >> 6)) * 2) * 4) * 512 + lane * 8;
#pragma unroll
    for (int st = 0; st < 8; st++)
      kc[st] = *(const bf16x8*)(kb8 + st * 512);
  }

  f32x16 acc0 = {}, acc1 = {};
  float lrow = 0.f;
  int qglob = qbase + q31;
  const float SC = 0.12f * 1.44269504f;

  for (int ti = 0; ti < nt; ti++) {
    int k0 = kstart + ti * 64;
    int kblk = k0 >> 6;
    const ushort* vb8 = vfr + ((((size_t)h * 32 + kblk) * 2) * 4) * 512 + lane * 8;
    f32x16 cA = {}, cB = {};
    __builtin_amdgcn_s_setprio(1);
#pragma unroll
    for (int st = 0; st < 4; st++) {
      cA = __builtin_amdgcn_mfma_f32_32x32x16_bf16(kc[st], qf[st], cA, 0, 0, 0);
      cB = __builtin_amdgcn_mfma_f32_32x32x16_bf16(kc[4 + st], qf[st], cB, 0, 0, 0);
    }
    __builtin_amdgcn_s_setprio(0);
    // refill K for next tile + load V now; latency hides under softmax/pack
    if (ti + 1 < nt) {
      const ushort* nk = kfr + ((((size_t)h * 32 + kblk + 1) * 2) * 4) * 512 + lane * 8;
#pragma unroll
      for (int st = 0; st < 8; st++)
        kc[st] = *(const bf16x8*)(nk + st * 512);
    }
    bf16x8 vv[8];
#pragma unroll
    for (int st = 0; st < 8; st++)
      vv[st] = *(const bf16x8*)(vb8 + st * 512);
    __builtin_amdgcn_sched_barrier(0);   // pin load issue above the VALU section
    float p[32];
#pragma unroll
    for (int r = 0; r < 16; r++) {
      float sA = cA[r] * SC;
      float sB = cB[r] * SC;
      if (fin) {
        int key = k0 + (r & 3) + 8 * (r >> 2) + 4 * hi;
        if (key > qglob)      sA = -1e30f;
        if (key + 32 > qglob) sB = -1e30f;
      }
      p[r] = sA;
      p[16 + r] = sB;
    }
    float rs0 = 0.f, rs1 = 0.f;
#pragma unroll
    for (int r = 0; r < 16; r++) {
      p[r]      = exp2f(p[r]);      rs0 += p[r];
      p[16 + r] = exp2f(p[16 + r]); rs1 += p[16 + r];
    }
    float rs = rs0 + rs1;
    rs += __shfl_xor(rs, 32, 64);
    lrow += rs;
    unsigned int pw[16], sw[16];
#pragma unroll
    for (int j = 0; j < 16; j++)
      pw[j] = pk2(p[2 * j], p[2 * j + 1]);
#pragma unroll
    for (int j = 0; j < 16; j++)
      sw[j] = __shfl_xor(pw[j], 32, 64);
    u32x4 u0, u1, u2, u3;
    u0[0] = hi ? sw[2]  : pw[0];
    u0[1] = hi ? sw[3]  : pw[1];
    u0[2] = hi ? pw[2]  : sw[0];
    u0[3] = hi ? pw[3]  : sw[1];
    u1[0] = hi ? sw[6]  : pw[4];
    u1[1] = hi ? sw[7]  : pw[5];
    u1[2] = hi ? pw[6]  : sw[4];
    u1[3] = hi ? pw[7]  : sw[5];
    u2[0] = hi ? sw[10] : pw[8];
    u2[1] = hi ? sw[11] : pw[9];
    u2[2] = hi ? pw[10] : sw[8];
    u2[3] = hi ? pw[11] : sw[9];
    u3[0] = hi ? sw[14] : pw[12];
    u3[1] = hi ? sw[15] : pw[13];
    u3[2] = hi ? pw[14] : sw[12];
    u3[3] = hi ? pw[15] : sw[13];
    bf16x8 pbA0 = __builtin_bit_cast(bf16x8, u0);
    bf16x8 pbA1 = __builtin_bit_cast(bf16x8, u1);
    bf16x8 pbB0 = __builtin_bit_cast(bf16x8, u2);
    bf16x8 pbB1 = __builtin_bit_cast(bf16x8, u3);
    __builtin_amdgcn_s_setprio(1);
    acc0 = __builtin_amdgcn_mfma_f32_32x32x16_bf16(vv[0], pbA0, acc0, 0, 0, 0);
    acc1 = __builtin_amdgcn_mfma_f32_32x32x16_bf16(vv[4], pbA0, acc1, 0, 0, 0);
    acc0 = __builtin_amdgcn_mfma_f32_32x32x16_bf16(vv[1], pbA1, acc0, 0, 0, 0);
    acc1 = __builtin_amdgcn_mfma_f32_32x32x16_bf16(vv[5], pbA1, acc1, 0, 0, 0);
    acc0 = __builtin_amdgcn_mfma_f32_32x32x16_bf16(vv[2], pbB0, acc0, 0, 0, 0);
    acc1 = __builtin_amdgcn_mfma_f32_32x32x16_bf16(vv[6], pbB0, acc1, 0, 0, 0);
    acc0 = __builtin_amdgcn_mfma_f32_32x32x16_bf16(vv[3], pbB1, acc0, 0, 0, 0);
    acc1 = __builtin_amdgcn_mfma_f32_32x32x16_bf16(vv[7], pbB1, acc1, 0, 0, 0);
    __builtin_amdgcn_s_setprio(0);
  }
  ushort* rec = parts + (size_t)(h * 288 + s) * 2176;
#pragma unroll
  for (int r = 0; r < 16; r++) {
    int d = (r & 3) + 8 * (r >> 2) + 4 * hi;
    rec[q31 * 64 + d]      = f2bf(acc0[r]);
    rec[q31 * 64 + 32 + d] = f2bf(acc1[r]);
  }
  if (!hi)
    *(float*)((char*)rec + 4096 + q31 * 4) = lrow;
}

// ---------- 4b) merge split-K partials: pure sum; 2 rows/wave, u32 loads ----------
__global__ __launch_bounds__(256) void attn_merge(const ushort* __restrict__ parts,
                                                  ushort* __restrict__ o) {
  int w = threadIdx.x >> 6, lane = threadIdx.x & 63;
  int idx = blockIdx.x * 8 + w * 2 + (lane >> 5);   // (h*64 + qt)*32 + r
  int l32 = lane & 31;
  int r = idx & 31;
  int rec_i = idx >> 5;
  int qt = rec_i & 63, h = rec_i >> 6;
  int g = qt >> 3, rr = qt & 7;
  int nch = g + 1;
  int off = qt + 4 * g * (g - 1) + rr * g;
  const ushort* base = parts + (size_t)(h * 288 + off) * 2176;
  float L = 0.f, ox = 0.f, oy = 0.f;
#pragma unroll
  for (int i = 0; i < 8; i++) {
    if (i < nch) {
      L += *(const float*)((const char*)base + i * 4352 + 4096 + r * 4);
      unsigned int u = *(const unsigned int*)(base + i * 2176 + r * 64 + l32 * 2);
      ox += bf2f((ushort)(u & 0xffffu));
      oy += bf2f((ushort)(u >> 16));
    }
  }
  float invL = 1.f / L;
  unsigned int o2 = pk2(ox * invL, oy * invL);
  *(unsigned int*)(o + (size_t)(qt * 32 + r) * DIM + h * HD + l32 * 2) = o2;
}

// ---------- 6) expmap (wave-per-token, no barriers) ----------
__global__ void expmap_kernel(const float* __restrict__ y2,
                              const float* __restrict__ ref,
                              float* __restrict__ yout) {
  int w = threadIdx.x >> 6, lane = threadIdx.x & 63;
  int t = blockIdx.x * 4 + w;
  const float4* Rp = (const float4*)(ref + (size_t)t * DIM);
  const float4* Vp = (const float4*)(y2 + (size_t)t * DIM);
  float4 X[4], V[4];
  float xn2 = 0.f, vn2 = 0.f, xv = 0.f;
#pragma unroll
  for (int i = 0; i < 4; i++) {
    int e = i * 64 + lane;
    float4 Xi = Rp[e], Vi = Vp[e];
    X[i] = Xi; V[i] = Vi;
    xn2 += Xi.x * Xi.x + Xi.y * Xi.y + Xi.z * Xi.z + Xi.w * Xi.w;
    vn2 += Vi.x * Vi.x + Vi.y * Vi.y + Vi.z * Vi.z + Vi.w * Vi.w;
    xv  += Xi.x * Vi.x + Xi.y * Vi.y + Xi.z * Vi.z + Xi.w * Vi.w;
  }
  xn2 = waveSum(xn2);
  vn2 = waveSum(vn2);
  xv  = waveSum(xv);
  float vn  = sqrtf(vn2);
  float sf  = 2.f / (1.f + xn2);
  float arg = sqrtf(fminf(fmaxf(0.5f * sf * vn2, 0.f), 8.f));
  float scl = tanhf(arg) / (vn + EPSF);
  float yn2 = scl * scl * vn2;
  float ip  = scl * xv;
  float A = 1.f + 2.f * ip + yn2;
  float B = (1.f - xn2) * scl;
  float den = fmaxf(1.f + 2.f * ip + xn2 * yn2, EPSF);
  float invden = 1.f / den;
  float4* outp = (float4*)(yout + (size_t)t * DIM);
#pragma unroll
  for (int i = 0; i < 4; i++) {
    float4 o;
    o.x = (A * X[i].x + B * V[i].x) * invden;
    o.y = (A * X[i].y + B * V[i].y) * invden;
    o.z = (A * X[i].z + B * V[i].z) * invden;
    o.w = (A * X[i].w + B * V[i].w) * invden;
    outp[i * 64 + lane] = o;
  }
}

// ---------- launch ----------
extern "C" void kernel_launch(void* const* d_in, const int* in_sizes, int n_in,
                              void* d_out, int out_size, void* d_ws, size_t ws_size,
                              hipStream_t stream) {
  const float* x        = (const float*)d_in[0];
  const float* qkv_w    = (const float*)d_in[1];
  const float* c_proj_w = (const float*)d_in[2];
  float* out = (float*)d_out;
  char*  W   = (char*)d_ws;

  ushort* qkvw_bf   = (ushort*)(W);             // [0, 6MB)
  ushort* cprojw_bf = (ushort*)(W + 6  * MB);   // [6, 8MB)
  ushort* xhyp_bf   = (ushort*)(W + 8  * MB);   // [8, 12MB)  reused as attn out o
  float*  y2        = (float*) (W + 12 * MB);   // [12, 36MB) shared: parts then y2
  ushort* parts     = (ushort*)(W + 12 * MB);   // 20.1 MB (dead before y2 written)
  ushort* qfrag     = (ushort*)(W + 36 * MB);   // [36, 40MB)
  ushort* kfrag     = (ushort*)(W + 40 * MB);   // [40, 44MB)
  ushort* vfrag     = (ushort*)(W + 44 * MB);   // [44, 48MB)
  ushort* obuf      = xhyp_bf;
  float*  ref       = out + (size_t)T_SEQ * DIM;

  logmap_cvt<<<T_SEQ / 4 + 2048, 256, 0, stream>>>(x, xhyp_bf, ref, qkv_w, c_proj_w,
                                                   qkvw_bf, cprojw_bf);
  gemm_bf16<128, 1><<<dim3(HD3 / 128, T_SEQ / 128), 256, 0, stream>>>(
      xhyp_bf, qkvw_bf, nullptr, qfrag, kfrag, vfrag, T_SEQ, HD3, DIM);
  attn_mfma<<<1152, 256, 0, stream>>>(qfrag, kfrag, vfrag, parts);
  attn_merge<<<4096, 256, 0, stream>>>(parts, obuf);
  gemm_bf16<64, 0><<<dim3(DIM / 128, T_SEQ / 64), 256, 0, stream>>>(
      obuf, cprojw_bf, y2, nullptr, nullptr, nullptr, T_SEQ, DIM, DIM);
  expmap_kernel<<<T_SEQ / 4, 256, 0, stream>>>(y2, ref, out);
}